// Round 5
// baseline (316.925 us; speedup 1.0000x reference)
//
#include <hip/hip_runtime.h>

#define BATCH 32
#define CDIM 512
#define NCL 27
#define HWDIM 3136            // 56*56
#define NPIX (BATCH * HWDIM)  // 100352
#define TILES_PER_B 49        // 3136/64
#define NBLK (NPIX / 64)      // 1568 blocks, 64 pixels each
#define NCHUNK 16             // 512 / 32 channels per MFMA K-step

typedef __attribute__((ext_vector_type(8))) short bf16x8;
typedef __attribute__((ext_vector_type(4))) float f32x4;

union I4B { int4 i; bf16x8 b; };

// ---------------------------------------------------------------------------
// Kernel 1: normalize codebook rows and emit MFMA B-fragments (hi/lo bf16
// split) in the exact per-lane order the main kernel consumes:
// wsB ushort index = ((chunk*4 + h*2 + part)*64 + lane)*8 + j
// where B[k][n]: n = (lane&15)+16h, k = chunk*32 + (lane>>4)*8 + j.
// Rows n>=27 are zero. part0 = hi (truncated), part1 = lo (RNE residual).
// ---------------------------------------------------------------------------
__global__ void prep_clusters_k(const float* __restrict__ cl,
                                unsigned short* __restrict__ wsB) {
    __shared__ float part[NCL][8];
    __shared__ float rnl[32];
    const int t = threadIdx.x;  // 256
    if (t < NCL * 8) {
        const int n = t >> 3, seg = t & 7;
        const float* p = cl + n * CDIM + seg * 64;
        float s = 0.f;
        for (int k = 0; k < 64; ++k) s += p[k] * p[k];
        part[n][seg] = s;
    }
    __syncthreads();
    if (t < 32) {
        float r = 0.f;
        if (t < NCL) {
            float s = 0.f;
#pragma unroll
            for (int k = 0; k < 8; ++k) s += part[t][k];
            r = 1.f / fmaxf(sqrtf(s), 1e-12f);
        }
        rnl[t] = r;
    }
    __syncthreads();
    for (int idx = t; idx < NCHUNK * 2 * 64 * 8; idx += 256) {
        const int j = idx & 7;
        const int lane = (idx >> 3) & 63;
        const int h = (idx >> 9) & 1;
        const int chunk = idx >> 10;
        const int n = 16 * h + (lane & 15);
        const int c = chunk * 32 + ((lane >> 4) << 3) + j;
        const float w = (n < NCL) ? cl[n * CDIM + c] * rnl[n] : 0.f;
        const unsigned int u = __float_as_uint(w);
        const unsigned short hi = (unsigned short)(u >> 16);
        const float hf = __uint_as_float(u & 0xffff0000u);
        const float lf = w - hf;  // exact
        const unsigned int ul = __float_as_uint(lf);
        const unsigned short lo =
            (unsigned short)((ul + 0x7fffu + ((ul >> 16) & 1u)) >> 16);
        const size_t base = ((size_t)(chunk * 4 + h * 2) * 64 + lane) * 8 + j;
        wsB[base] = hi;
        wsB[base + 512] = lo;  // part stride = 64*8
    }
}

// ---------------------------------------------------------------------------
// Kernel 2: main. 1568 blocks x 256 threads (4 waves). Wave w owns pixels
// tile*64 + w*16 .. +15, all 512 channels, all 32 (padded) clusters.
// K-loop: 8 x fp32 loads/lane (A tile), hi/lo bf16 split, 6 MFMAs
// (hihi, hilo, lohi x two cluster halves); x & B prefetched 1 chunk ahead.
// Epilogue: ss via shuffles, softmax in C-layout registers, probs
// transposed through LDS, coalesced 256B stores, per-block loss partial.
// ---------------------------------------------------------------------------
__global__ __launch_bounds__(256, 4) void cluster_main_k(
    const float* __restrict__ x, const unsigned short* __restrict__ wsB,
    float* __restrict__ out_probs,  // = d_out + 1
    float* __restrict__ partials) {
    __shared__ float pr[32][69];    // probs transpose, padded
    __shared__ float ss_sm[4][16];  // per-wave pixel |x|^2
    __shared__ float lossw[4];

    const int lane = threadIdx.x;  // 0..63
    const int w = threadIdx.y;     // wave 0..3
    const int b = blockIdx.x / TILES_PER_B;
    const int tile = blockIdx.x % TILES_PER_B;
    const int m = lane & 15;  // A-row (pixel) for this lane
    const int q = lane >> 4;  // k-quad

    const int hw = tile * 64 + w * 16 + m;
    const float* px0 = x + ((size_t)b * CDIM + (q << 3)) * HWDIM + hw;
    const int4* wsb4 = (const int4*)wsB;

    f32x4 acc0 = {0.f, 0.f, 0.f, 0.f};
    f32x4 acc1 = {0.f, 0.f, 0.f, 0.f};
    float ssq = 0.f;

    float xv[8], xn[8];
    int4 bcur[4], bnxt[4];
#pragma unroll
    for (int j = 0; j < 8; ++j) xv[j] = px0[(size_t)j * HWDIM];
#pragma unroll
    for (int k = 0; k < 4; ++k) bcur[k] = wsb4[k * 64 + lane];

    for (int chunk = 0; chunk < NCHUNK; ++chunk) {
        if (chunk < NCHUNK - 1) {
            const float* pn = px0 + (size_t)(chunk + 1) * 32 * HWDIM;
#pragma unroll
            for (int j = 0; j < 8; ++j) xn[j] = pn[(size_t)j * HWDIM];
#pragma unroll
            for (int k = 0; k < 4; ++k)
                bnxt[k] = wsb4[((chunk + 1) * 4 + k) * 64 + lane];
        }
        // split xv into bf16 hi (truncate) + lo (truncate of exact residual)
        I4B Ahi, Alo;
#pragma unroll
        for (int d = 0; d < 4; ++d) {
            const float x0 = xv[2 * d], x1 = xv[2 * d + 1];
            ssq += x0 * x0 + x1 * x1;
            const unsigned int u0 = __float_as_uint(x0);
            const unsigned int u1 = __float_as_uint(x1);
            Ahi.i.x;  // no-op to keep union active (removed below)
            ((unsigned int*)&Ahi.i)[d] = (u0 >> 16) | (u1 & 0xffff0000u);
            const float h0 = __uint_as_float(u0 & 0xffff0000u);
            const float h1 = __uint_as_float(u1 & 0xffff0000u);
            const unsigned int l0 = __float_as_uint(x0 - h0);
            const unsigned int l1 = __float_as_uint(x1 - h1);
            ((unsigned int*)&Alo.i)[d] = (l0 >> 16) | (l1 & 0xffff0000u);
        }
        I4B B0h, B0l, B1h, B1l;
        B0h.i = bcur[0]; B0l.i = bcur[1]; B1h.i = bcur[2]; B1l.i = bcur[3];
        acc0 = __builtin_amdgcn_mfma_f32_16x16x32_bf16(Ahi.b, B0h.b, acc0, 0, 0, 0);
        acc1 = __builtin_amdgcn_mfma_f32_16x16x32_bf16(Ahi.b, B1h.b, acc1, 0, 0, 0);
        acc0 = __builtin_amdgcn_mfma_f32_16x16x32_bf16(Ahi.b, B0l.b, acc0, 0, 0, 0);
        acc1 = __builtin_amdgcn_mfma_f32_16x16x32_bf16(Ahi.b, B1l.b, acc1, 0, 0, 0);
        acc0 = __builtin_amdgcn_mfma_f32_16x16x32_bf16(Alo.b, B0h.b, acc0, 0, 0, 0);
        acc1 = __builtin_amdgcn_mfma_f32_16x16x32_bf16(Alo.b, B1h.b, acc1, 0, 0, 0);
#pragma unroll
        for (int j = 0; j < 8; ++j) xv[j] = xn[j];
#pragma unroll
        for (int k = 0; k < 4; ++k) bcur[k] = bnxt[k];
    }

    // per-pixel |x|^2: sum the 4 k-quads (lanes m, m+16, m+32, m+48)
    ssq += __shfl_xor(ssq, 16, 64);
    ssq += __shfl_xor(ssq, 32, 64);
    if (lane < 16) ss_sm[w][lane] = ssq;  // wave-internal, no barrier needed

    // softmax in C-layout: lane holds (pixel row = q*4+r, cluster col & col+16)
    const int col = m;
    const bool v1 = (col + 16) < NCL;  // second half valid (col < 11)
    float dot = 0.f;
#pragma unroll
    for (int r = 0; r < 4; ++r) {
        const float rn = 1.f / fmaxf(sqrtf(ss_sm[w][q * 4 + r]), 1e-12f);
        const float s0 = acc0[r] * rn;
        const float s1 = acc1[r] * rn;
        float mx = v1 ? fmaxf(s0, s1) : s0;
#pragma unroll
        for (int d = 1; d < 16; d <<= 1) mx = fmaxf(mx, __shfl_xor(mx, d, 64));
        const float e0 = __expf(2.f * (s0 - mx));
        const float e1 = v1 ? __expf(2.f * (s1 - mx)) : 0.f;
        float z = e0 + e1;
#pragma unroll
        for (int d = 1; d < 16; d <<= 1) z += __shfl_xor(z, d, 64);
        const float rz = 1.f / z;
        const float p0 = e0 * rz;
        const float p1 = e1 * rz;
        const int px = w * 16 + q * 4 + r;
        pr[col][px] = p0;
        pr[col + 16][px] = p1;
        dot += p0 * s0 + p1 * s1;
    }
#pragma unroll
    for (int d = 1; d < 64; d <<= 1) dot += __shfl_xor(dot, d, 64);
    if (lane == 0) lossw[w] = dot;
    __syncthreads();

    // coalesced prob stores: 27 rows x 64 contiguous floats
    const int t = w * 64 + lane;
    const int px = t & 63;
    float* ob = out_probs + (size_t)b * NCL * HWDIM + tile * 64 + px;
    for (int n = t >> 6; n < NCL; n += 4) ob[(size_t)n * HWDIM] = pr[n][px];

    if (t == 0)
        partials[blockIdx.x] = lossw[0] + lossw[1] + lossw[2] + lossw[3];
}

// ---------------------------------------------------------------------------
// Kernel 3: reduce 1568 per-block partials -> loss scalar
// ---------------------------------------------------------------------------
__global__ void loss_final_k(const float* __restrict__ partials,
                             float* __restrict__ out) {
    __shared__ float sm[4];
    const int t = threadIdx.x;  // 256
    float s = 0.f;
    for (int i = t; i < NBLK; i += 256) s += partials[i];
#pragma unroll
    for (int off = 32; off > 0; off >>= 1) s += __shfl_down(s, off, 64);
    if ((t & 63) == 0) sm[t >> 6] = s;
    __syncthreads();
    if (t == 0) {
        const float tot = sm[0] + sm[1] + sm[2] + sm[3];
        out[0] = -(tot / (float)NPIX);
    }
}

extern "C" void kernel_launch(void* const* d_in, const int* in_sizes, int n_in,
                              void* d_out, int out_size, void* d_ws,
                              size_t ws_size, hipStream_t stream) {
    const float* x = (const float*)d_in[0];        // [32,512,56,56]
    const float* clusters = (const float*)d_in[1]; // [27,512]
    float* out = (float*)d_out;                    // [loss | probs]
    unsigned short* wsB = (unsigned short*)d_ws;   // B frags: 64K ushorts
    float* partials = (float*)(wsB + NCHUNK * 4 * 64 * 8);  // 1568 floats

    prep_clusters_k<<<1, 256, 0, stream>>>(clusters, wsB);
    cluster_main_k<<<NBLK, dim3(64, 4), 0, stream>>>(x, wsB, out + 1, partials);
    loss_final_k<<<1, 256, 0, stream>>>(partials, out);
}

// Round 6
// 309.420 us; speedup vs baseline: 1.0243x; 1.0243x over previous
//
#include <hip/hip_runtime.h>

#define BATCH 32
#define CDIM 512
#define NCL 27
#define HWDIM 3136            // 56*56
#define NPIX (BATCH * HWDIM)  // 100352
#define PXB 256               // pixels per block -> 1KB/channel contiguous
#define NBLK (NPIX / PXB)     // 392 blocks
#define NCHUNK 16             // 512 / 32 channels per K-chunk

typedef __attribute__((ext_vector_type(8))) short bf16x8;
typedef __attribute__((ext_vector_type(4))) float f32x4;

union I4B { int4 i; bf16x8 b; };

// ---------------------------------------------------------------------------
// Kernel 1: normalize codebook rows, emit MFMA B-fragments (hi/lo bf16
// split): wsB ushort index = ((chunk*4 + h*2 + part)*64 + lane)*8 + j,
// B[k][n]: n = (lane&15)+16h, k = chunk*32 + (lane>>4)*8 + j. n>=27 zero.
// ---------------------------------------------------------------------------
__global__ void prep_clusters_k(const float* __restrict__ cl,
                                unsigned short* __restrict__ wsB) {
    __shared__ float part[NCL][8];
    __shared__ float rnl[32];
    const int t = threadIdx.x;  // 256
    if (t < NCL * 8) {
        const int n = t >> 3, seg = t & 7;
        const float* p = cl + n * CDIM + seg * 64;
        float s = 0.f;
        for (int k = 0; k < 64; ++k) s += p[k] * p[k];
        part[n][seg] = s;
    }
    __syncthreads();
    if (t < 32) {
        float r = 0.f;
        if (t < NCL) {
            float s = 0.f;
#pragma unroll
            for (int k = 0; k < 8; ++k) s += part[t][k];
            r = 1.f / fmaxf(sqrtf(s), 1e-12f);
        }
        rnl[t] = r;
    }
    __syncthreads();
    for (int idx = t; idx < NCHUNK * 2 * 64 * 8; idx += 256) {
        const int j = idx & 7;
        const int lane = (idx >> 3) & 63;
        const int h = (idx >> 9) & 1;
        const int chunk = idx >> 10;
        const int n = 16 * h + (lane & 15);
        const int c = chunk * 32 + ((lane >> 4) << 3) + j;
        const float w = (n < NCL) ? cl[n * CDIM + c] * rnl[n] : 0.f;
        const unsigned int u = __float_as_uint(w);
        const unsigned short hi = (unsigned short)(u >> 16);
        const float hf = __uint_as_float(u & 0xffff0000u);
        const float lf = w - hf;  // exact
        const unsigned int ul = __float_as_uint(lf);
        const unsigned short lo =
            (unsigned short)((ul + 0x7fffu + ((ul >> 16) & 1u)) >> 16);
        const size_t base = ((size_t)(chunk * 4 + h * 2) * 64 + lane) * 8 + j;
        wsB[base] = hi;
        wsB[base + 512] = lo;  // part stride = 64*8
    }
}

// ---------------------------------------------------------------------------
// Kernel 2: main. 392 blocks x 256 threads (4 waves). Wave w owns 64 px
// (block px w*64..w*64+63), all 512 channels, 32 padded clusters, as FOUR
// 16x16x32 MFMA tiles with row mapping px = 4*m + tile: lane m's float4
// x-load (px 4m..4m+3, channel q*8+j) provides component i directly as
// tile i's A element — no cross-lane moves. Per chunk: 8 dwordx4 x-loads
// (256 B contiguous per channel per wave, 1 KB per block), 4 dwordx4
// B-loads, hi/lo bf16 split, 24 MFMAs; 1-chunk-ahead prefetch.
// ---------------------------------------------------------------------------
__global__ __launch_bounds__(256, 2) void cluster_main_k(
    const float* __restrict__ x, const unsigned short* __restrict__ wsB,
    float* __restrict__ out_probs,  // = d_out + 1
    float* __restrict__ partials) {
    __shared__ float pr[NCL][PXB + 1];  // 27756 B, stride 257 (conflict-free)
    __shared__ float ss_sm[4][64];
    __shared__ float lossw[4];

    const int lane = threadIdx.x;  // 0..63
    const int w = threadIdx.y;     // wave 0..3
    const int m = lane & 15;
    const int q = lane >> 4;

    // lane's pixel quad (16-px groups never straddle a batch: 16 | 3136)
    const int p0 = blockIdx.x * PXB + w * 64 + 4 * m;
    const int b = p0 / HWDIM;
    const int hw0 = p0 - b * HWDIM;
    const float* xl = x + (size_t)b * CDIM * HWDIM + hw0;
    const int4* wsb4 = (const int4*)wsB;

    f32x4 acc[4][2];
#pragma unroll
    for (int i = 0; i < 4; ++i)
#pragma unroll
        for (int h = 0; h < 2; ++h)
            acc[i][h] = (f32x4){0.f, 0.f, 0.f, 0.f};
    float ssq[4] = {0.f, 0.f, 0.f, 0.f};

    float4 xv[8], xn[8];
    int4 bcur[4], bnxt[4];
#pragma unroll
    for (int j = 0; j < 8; ++j)
        xv[j] = *(const float4*)(xl + (size_t)(q * 8 + j) * HWDIM);
#pragma unroll
    for (int k = 0; k < 4; ++k) bcur[k] = wsb4[k * 64 + lane];

    for (int chunk = 0; chunk < NCHUNK; ++chunk) {
        if (chunk < NCHUNK - 1) {
            const float* xc = xl + (size_t)((chunk + 1) * 32 + q * 8) * HWDIM;
#pragma unroll
            for (int j = 0; j < 8; ++j)
                xn[j] = *(const float4*)(xc + (size_t)j * HWDIM);
#pragma unroll
            for (int k = 0; k < 4; ++k)
                bnxt[k] = wsb4[((chunk + 1) * 4 + k) * 64 + lane];
        }
#pragma unroll
        for (int j = 0; j < 8; ++j) {
            ssq[0] += xv[j].x * xv[j].x;
            ssq[1] += xv[j].y * xv[j].y;
            ssq[2] += xv[j].z * xv[j].z;
            ssq[3] += xv[j].w * xv[j].w;
        }
        I4B B0h, B0l, B1h, B1l;
        B0h.i = bcur[0]; B0l.i = bcur[1]; B1h.i = bcur[2]; B1l.i = bcur[3];
#pragma unroll
        for (int i = 0; i < 4; ++i) {
            I4B Ahi, Alo;
#pragma unroll
            for (int d = 0; d < 4; ++d) {
                const float x0 = ((const float*)&xv[2 * d])[i];
                const float x1 = ((const float*)&xv[2 * d + 1])[i];
                const unsigned int u0 = __float_as_uint(x0);
                const unsigned int u1 = __float_as_uint(x1);
                ((unsigned int*)&Ahi.i)[d] = (u0 >> 16) | (u1 & 0xffff0000u);
                const float h0 = __uint_as_float(u0 & 0xffff0000u);
                const float h1 = __uint_as_float(u1 & 0xffff0000u);
                const unsigned int l0 = __float_as_uint(x0 - h0);
                const unsigned int l1 = __float_as_uint(x1 - h1);
                ((unsigned int*)&Alo.i)[d] = (l0 >> 16) | (l1 & 0xffff0000u);
            }
            acc[i][0] = __builtin_amdgcn_mfma_f32_16x16x32_bf16(Ahi.b, B0h.b, acc[i][0], 0, 0, 0);
            acc[i][1] = __builtin_amdgcn_mfma_f32_16x16x32_bf16(Ahi.b, B1h.b, acc[i][1], 0, 0, 0);
            acc[i][0] = __builtin_amdgcn_mfma_f32_16x16x32_bf16(Ahi.b, B0l.b, acc[i][0], 0, 0, 0);
            acc[i][1] = __builtin_amdgcn_mfma_f32_16x16x32_bf16(Ahi.b, B1l.b, acc[i][1], 0, 0, 0);
            acc[i][0] = __builtin_amdgcn_mfma_f32_16x16x32_bf16(Alo.b, B0h.b, acc[i][0], 0, 0, 0);
            acc[i][1] = __builtin_amdgcn_mfma_f32_16x16x32_bf16(Alo.b, B1h.b, acc[i][1], 0, 0, 0);
        }
#pragma unroll
        for (int j = 0; j < 8; ++j) xv[j] = xn[j];
#pragma unroll
        for (int k = 0; k < 4; ++k) bcur[k] = bnxt[k];
    }

    // |x|^2: lane covers channels of its q only -> reduce across q-groups;
    // then lane m holds full ssq for px 4m+i (i=0..3)
#pragma unroll
    for (int i = 0; i < 4; ++i) {
        ssq[i] += __shfl_xor(ssq[i], 16, 64);
        ssq[i] += __shfl_xor(ssq[i], 32, 64);
    }
    if (lane < 16)
        *(float4*)&ss_sm[w][4 * lane] =
            (float4){ssq[0], ssq[1], ssq[2], ssq[3]};

    // softmax in C-layout: tile i, reg r -> px = 4*(q*4+r)+i, cols m & m+16
    const int col = m;
    const bool v1 = (col + 16) < NCL;
    float dot = 0.f;
#pragma unroll
    for (int i = 0; i < 4; ++i) {
#pragma unroll
        for (int r = 0; r < 4; ++r) {
            const int pxl = 4 * (q * 4 + r) + i;  // 0..63 within wave
            const float rn = 1.f / fmaxf(sqrtf(ss_sm[w][pxl]), 1e-12f);
            const float s0 = acc[i][0][r] * rn;
            const float s1 = acc[i][1][r] * rn;
            float mx = v1 ? fmaxf(s0, s1) : s0;
#pragma unroll
            for (int d = 1; d < 16; d <<= 1)
                mx = fmaxf(mx, __shfl_xor(mx, d, 64));
            const float e0 = __expf(2.f * (s0 - mx));
            const float e1 = v1 ? __expf(2.f * (s1 - mx)) : 0.f;
            float z = e0 + e1;
#pragma unroll
            for (int d = 1; d < 16; d <<= 1) z += __shfl_xor(z, d, 64);
            const float rz = 1.f / z;
            const float pp0 = e0 * rz;
            const float pp1 = e1 * rz;
            pr[col][w * 64 + pxl] = pp0;
            if (v1) pr[col + 16][w * 64 + pxl] = pp1;
            dot += pp0 * s0 + pp1 * s1;
        }
    }
#pragma unroll
    for (int d = 1; d < 64; d <<= 1) dot += __shfl_xor(dot, d, 64);
    if (lane == 0) lossw[w] = dot;
    __syncthreads();

    // coalesced prob stores: 27 rows x 256 contiguous floats
    const int t = w * 64 + lane;
    const int pflat = blockIdx.x * PXB + t;
    const int bb = pflat / HWDIM;
    const int hh = pflat - bb * HWDIM;
    float* ob = out_probs + (size_t)bb * NCL * HWDIM + hh;
#pragma unroll
    for (int n = 0; n < NCL; ++n) ob[(size_t)n * HWDIM] = pr[n][t];

    if (t == 0)
        partials[blockIdx.x] = lossw[0] + lossw[1] + lossw[2] + lossw[3];
}

// ---------------------------------------------------------------------------
// Kernel 3: reduce 392 per-block partials -> loss scalar
// ---------------------------------------------------------------------------
__global__ void loss_final_k(const float* __restrict__ partials,
                             float* __restrict__ out) {
    __shared__ float sm[4];
    const int t = threadIdx.x;  // 256
    float s = 0.f;
    for (int i = t; i < NBLK; i += 256) s += partials[i];
#pragma unroll
    for (int off = 32; off > 0; off >>= 1) s += __shfl_down(s, off, 64);
    if ((t & 63) == 0) sm[t >> 6] = s;
    __syncthreads();
    if (t == 0) {
        const float tot = sm[0] + sm[1] + sm[2] + sm[3];
        out[0] = -(tot / (float)NPIX);
    }
}

extern "C" void kernel_launch(void* const* d_in, const int* in_sizes, int n_in,
                              void* d_out, int out_size, void* d_ws,
                              size_t ws_size, hipStream_t stream) {
    const float* x = (const float*)d_in[0];        // [32,512,56,56]
    const float* clusters = (const float*)d_in[1]; // [27,512]
    float* out = (float*)d_out;                    // [loss | probs]
    unsigned short* wsB = (unsigned short*)d_ws;   // B frags: 32768 ushorts
    float* partials = (float*)(wsB + NCHUNK * 4 * 64 * 8);  // 392 floats

    prep_clusters_k<<<1, 256, 0, stream>>>(clusters, wsB);
    cluster_main_k<<<NBLK, dim3(64, 4), 0, stream>>>(x, wsB, out + 1, partials);
    loss_final_k<<<1, 256, 0, stream>>>(partials, out);
}